// Round 7
// baseline (493.649 us; speedup 1.0000x reference)
//
#include <hip/hip_runtime.h>
#include <math.h>

// Problem constants (from reference): B=64, T=2048, D=256
#define BB 64
#define TT 2048
#define D4 64             // D/4 -> one float4 per lane, one wave covers D
#define SS 64             // time segments
#define LL (TT / SS)      // 32 steps per segment
#define NSLOT (SS * BB)

// Native clang vector: elementwise ops, NT-store compatible.
typedef float f4 __attribute__((ext_vector_type(4)));

// Flag magic: top 16 bits 0x7E57 (bytes unequal) can never equal a
// repeated-byte ws poison pattern; low bits tag the slot.
#define FLAG_MAGIC(slot) (0x7E570000u | (unsigned)(slot))

// -------------------- math helpers --------------------

__device__ __forceinline__ float softplus_f(float x) {
    return (x > 0.f) ? (x + log1pf(expf(-x))) : log1pf(expf(x));
}

struct P4 { f4 k, s2, r, mu; };   // per-lane params for 4 chains
struct C4 { f4 A, bm, sQ; };      // per-step coefficients for 4 chains
struct P1 { float k, s2, r; };
struct C1 { float A, bm, sQ; };

__device__ __forceinline__ P1 sp1(float lk, float ls) {
    P1 o;
    o.k = softplus_f(lk) + 1e-6f;
    float s = softplus_f(ls) + 1e-6f;
    o.s2 = s * s;
    o.r = o.s2 / fmaxf(2.f * o.k, 1e-12f);
    return o;
}

__device__ __forceinline__ P4 load_params4(const f4* __restrict__ mu4,
                                           const f4* __restrict__ lk4,
                                           const f4* __restrict__ ls4,
                                           int lane) {
    f4 lk = lk4[lane], ls = ls4[lane], mu = mu4[lane];
    P4 p;
    P1 a;
    a = sp1(lk.x, ls.x); p.k.x = a.k; p.s2.x = a.s2; p.r.x = a.r;
    a = sp1(lk.y, ls.y); p.k.y = a.k; p.s2.y = a.s2; p.r.y = a.r;
    a = sp1(lk.z, ls.z); p.k.z = a.k; p.s2.z = a.s2; p.r.z = a.r;
    a = sp1(lk.w, ls.w); p.k.w = a.k; p.s2.w = a.s2; p.r.w = a.r;
    p.mu = mu;
    return p;
}

// Exact OU transition coefficients (A = exp(-k dt); Q exact w/ Taylor fallback).
__device__ __forceinline__ C1 ou_coeff(float dt, float kappa, float s2, float r,
                                       float mu) {
    C1 o;
    float e = kappa * dt;
    o.A = __expf(-e);
    float two = 2.f * e;
    float Qe = r * (1.f - o.A * o.A);
    float Qt = s2 * dt * fmaf(two * two, (1.f / 6.f), 1.f - e);
    float Q = (two < 1e-6f) ? Qt : Qe;
    o.sQ = sqrtf(Q);
    o.bm = mu * (1.f - o.A);
    return o;
}

__device__ __forceinline__ C4 coeff4(float dt, const P4& p) {
    C4 c;
    C1 o;
    o = ou_coeff(dt, p.k.x, p.s2.x, p.r.x, p.mu.x); c.A.x = o.A; c.bm.x = o.bm; c.sQ.x = o.sQ;
    o = ou_coeff(dt, p.k.y, p.s2.y, p.r.y, p.mu.y); c.A.y = o.A; c.bm.y = o.bm; c.sQ.y = o.sQ;
    o = ou_coeff(dt, p.k.z, p.s2.z, p.r.z, p.mu.z); c.A.z = o.A; c.bm.z = o.bm; c.sQ.z = o.sQ;
    o = ou_coeff(dt, p.k.w, p.s2.w, p.r.w, p.mu.w); c.A.w = o.A; c.bm.w = o.bm; c.sQ.w = o.sQ;
    return c;
}

__device__ __forceinline__ f4 sqrt4(const f4 v) {
    f4 r;
    r.x = sqrtf(v.x); r.y = sqrtf(v.y); r.z = sqrtf(v.z); r.w = sqrtf(v.w);
    return r;
}

// Recompute segment j's (P,U) directly from noise (rare fallback path; keeps
// correctness independent of dispatch order / flag visibility).
__device__ void recompute_seg(int j, const f4* __restrict__ np,
                              const float* __restrict__ ts, const P4& p,
                              f4* Pj, f4* Uj) {
    f4 U = {0.f, 0.f, 0.f, 0.f};
    f4 P = {1.f, 1.f, 1.f, 1.f};
    float dtprev = -1.f;
    C4 cc;
    const int t0 = j * LL;
    for (int i = 0; i < LL; ++i) {
        int t = t0 + i;
        float dt = 1e-6f;
        if (t >= 1) dt = fmaxf(ts[t] - ts[t - 1], 1e-6f);
        f4 n = np[(size_t)t * D4];
        if (dt != dtprev) { cc = coeff4(dt, p); dtprev = dt; }
        f4 cv = cc.sQ * n + cc.bm;
        f4 a = cc.A;
        if (j == 0 && i == 0) {
            cv = n * sqrt4(p.r) + p.mu;
            a = (f4){0.f, 0.f, 0.f, 0.f};
        }
        U = a * U + cv;
        P = P * a;
    }
    *Pj = P;
    *Uj = U;
}

// ==================== single-dispatch pipelined scan ====================
// Block = one wave = (segment s, chain b). Phase A: read this segment's noise
// ONCE, build (P,U) partials, keep innovations c[i] in registers, publish
// (P,U) + release-flag. Phase B: wait (sleep-backoff poll, 1 flag load/lane,
// 4 cache lines/column) for column predecessors, locally scan their (P,U)
// (L2-resident), then replay from registers and NT-store the output.
// No inclusive chain, no hot spin; timeout -> self-recompute (order-safe).
__global__ __launch_bounds__(64, 2) void ou_onepass(
    const float* __restrict__ ts, const f4* __restrict__ noise4,
    const f4* __restrict__ mu4, const f4* __restrict__ lk4,
    const f4* __restrict__ ls4,
    f4* __restrict__ Pw, f4* __restrict__ Uw, unsigned* __restrict__ flags,
    f4* __restrict__ out4) {
    const int lane = threadIdx.x;         // 0..63
    const int s = blockIdx.x / BB;        // s-major: low s dispatch first
    const int b = blockIdx.x % BB;
    const int t0 = s * LL;

    // lane i (< LL) holds dt for step t0+i; broadcast via shfl
    float dtv = 1e-6f;
    if (lane < LL) {
        int t = t0 + lane;
        if (t >= 1) dtv = fmaxf(ts[t] - ts[t - 1], 1e-6f);
    }

    P4 p = load_params4(mu4, lk4, ls4, lane);
    const f4* np = noise4 + (size_t)b * TT * D4 + lane;

    // ---------------- phase A: partials + c[] in registers ----------------
    f4 c[LL];
    f4 U = {0.f, 0.f, 0.f, 0.f};
    f4 P = {1.f, 1.f, 1.f, 1.f};
    float dtprev = -1.f;
    C4 cc;
#pragma unroll
    for (int i = 0; i < LL; ++i) {
        float dt = __shfl(dtv, i);
        f4 n = np[(size_t)(t0 + i) * D4];
        if (dt != dtprev) { cc = coeff4(dt, p); dtprev = dt; } // wave-uniform
        f4 cv = cc.sQ * n + cc.bm;
        f4 a = cc.A;
        if (s == 0 && i == 0) {            // fold initial condition
            cv = n * sqrt4(p.r) + p.mu;
            a = (f4){0.f, 0.f, 0.f, 0.f};  // absorbing
        }
        c[i] = cv;
        U = a * U + cv;
        P = P * a;
    }

    // publish partials (segment SS-1 is never read by anyone)
    if (s < SS - 1) {
        size_t idx = ((size_t)s * BB + b) * D4 + lane;
        Pw[idx] = P;
        Uw[idx] = U;
        __threadfence();
        if (lane == 0) {
            const int slot = b * SS + s;   // column-contiguous flag layout
            __hip_atomic_store(&flags[slot], FLAG_MAGIC(slot),
                               __ATOMIC_RELEASE, __HIP_MEMORY_SCOPE_AGENT);
        }
    }

    // ---------------- phase B: wait for predecessors, scan, replay ---------
    f4 y = {0.f, 0.f, 0.f, 0.f};
    if (s > 0) {
        const int myslot = b * SS + lane;
        const unsigned mymagic = FLAG_MAGIC(myslot);
        unsigned fv = 0;
        int tries = 0;
        for (;;) {
            fv = (lane < s)
                     ? __hip_atomic_load(&flags[myslot], __ATOMIC_ACQUIRE,
                                         __HIP_MEMORY_SCOPE_AGENT)
                     : mymagic;
            int ok = (lane >= s) || (fv == mymagic);
            if (__all(ok)) break;
            if (++tries > 20000) break;    // ~4 ms cap, then self-recompute
            __builtin_amdgcn_s_sleep(8);   // ~512 cy backoff: no spin storm
        }
        unsigned long long miss = __ballot(lane < s && fv != mymagic);

        f4 inc;
        if (miss & 1ull) {
            f4 Pj, Uj;
            recompute_seg(0, np, ts, p, &Pj, &Uj);
            inc = Uj;
        } else {
            inc = Uw[(size_t)b * D4 + lane];            // j = 0
        }
        for (int j = 1; j < s; ++j) {
            f4 Pj, Uj;
            if ((miss >> j) & 1ull) {
                recompute_seg(j, np, ts, p, &Pj, &Uj);
            } else {
                size_t idx = ((size_t)j * BB + b) * D4 + lane;
                Pj = Pw[idx];
                Uj = Uw[idx];
            }
            inc = Pj * inc + Uj;
        }
        y = inc;   // state at end of segment s-1
    }

    // replay from registers; only output-write traffic
    f4* op = out4 + (size_t)b * TT * D4 + lane;
    dtprev = -1.f;
#pragma unroll
    for (int i = 0; i < LL; ++i) {
        float dt = __shfl(dtv, i);
        if (dt != dtprev) { cc = coeff4(dt, p); dtprev = dt; }
        f4 a = cc.A;
        if (s == 0 && i == 0) a = (f4){0.f, 0.f, 0.f, 0.f};
        y = a * y + c[i];
        __builtin_nontemporal_store(y, op + (size_t)(t0 + i) * D4);
    }
}

// -------------------- last-resort fallback: plain per-chain scan ------------
__global__ __launch_bounds__(128) void ou_fallback(
    const float* __restrict__ ts, const float2* __restrict__ noise2,
    const float2* __restrict__ mu2, const float2* __restrict__ lk2,
    const float2* __restrict__ ls2, float2* __restrict__ out2) {
    __shared__ float dts[TT];
    const int tid = threadIdx.x;
    const int b = blockIdx.x;
    for (int i = tid; i < TT; i += 128) {
        float dt = 1e-6f;
        if (i >= 1) dt = fmaxf(ts[i] - ts[i - 1], 1e-6f);
        dts[i] = dt;
    }
    __syncthreads();

    float2 lk = lk2[tid], ls = ls2[tid], mu = mu2[tid];
    P1 px = sp1(lk.x, ls.x);
    P1 py = sp1(lk.y, ls.y);

    const float2* np = noise2 + (size_t)b * TT * 128 + tid;
    float2* op = out2 + (size_t)b * TT * 128 + tid;

    float2 n0 = np[0];
    float2 y;
    y.x = fmaf(n0.x, sqrtf(px.r), mu.x);
    y.y = fmaf(n0.y, sqrtf(py.r), mu.y);
    op[0] = y;

#pragma unroll 4
    for (int k = 1; k < TT; ++k) {
        float dt = dts[k];
        float2 n = np[(size_t)k * 128];
        C1 cx = ou_coeff(dt, px.k, px.s2, px.r, mu.x);
        C1 cy = ou_coeff(dt, py.k, py.s2, py.r, mu.y);
        y.x = fmaf(cx.A, y.x, fmaf(cx.sQ, n.x, cx.bm));
        y.y = fmaf(cy.A, y.y, fmaf(cy.sQ, n.y, cy.bm));
        op[(size_t)k * 128] = y;
    }
}

// -------------------- launch --------------------
extern "C" void kernel_launch(void* const* d_in, const int* in_sizes, int n_in,
                              void* d_out, int out_size, void* d_ws, size_t ws_size,
                              hipStream_t stream) {
    const float* ts = (const float*)d_in[0];
    const f4* noise4 = (const f4*)d_in[1];
    const f4* mu4 = (const f4*)d_in[2];
    const f4* lk4 = (const f4*)d_in[3];
    const f4* ls4 = (const f4*)d_in[4];
    f4* out4 = (f4*)d_out;

    const size_t seg = (size_t)SS * BB * D4; // f4 elements per ws buffer
    const size_t need = 2 * seg * sizeof(f4) + NSLOT * sizeof(unsigned);
    if (ws_size >= need) {
        f4* Pw = (f4*)d_ws;
        f4* Uw = Pw + seg;
        unsigned* flags = (unsigned*)(Uw + seg);
        ou_onepass<<<SS * BB, 64, 0, stream>>>(ts, noise4, mu4, lk4, ls4,
                                               Pw, Uw, flags, out4);
    } else {
        ou_fallback<<<BB, 128, 0, stream>>>(ts, (const float2*)d_in[1],
                                            (const float2*)d_in[2],
                                            (const float2*)d_in[3],
                                            (const float2*)d_in[4],
                                            (float2*)d_out);
    }
}

// Round 8
// 112.675 us; speedup vs baseline: 4.3812x; 4.3812x over previous
//
#include <hip/hip_runtime.h>
#include <math.h>

// Problem constants (from reference): B=64, T=2048, D=256
#define BB 64
#define TT 2048
#define D4 64             // D/4 -> one float4 per lane, one wave covers D
#define SS 64             // time segments
#define LL (TT / SS)      // 32 steps per segment
#define WPB 4             // waves per block (each wave owns one b, same s)
#define BPG (BB / WPB)    // b-groups per segment

// Native clang vector: elementwise ops, NT-load/store compatible.
typedef float f4 __attribute__((ext_vector_type(4)));

// -------------------- math helpers --------------------

__device__ __forceinline__ float softplus_f(float x) {
    // stable log1p(exp(x)) to match jax.nn.softplus
    return (x > 0.f) ? (x + log1pf(expf(-x))) : log1pf(expf(x));
}

struct P4 { f4 k, s2, r, mu; };   // per-lane params for 4 chains
struct C4 { f4 A, bm, sQ; };      // per-step coefficients for 4 chains
struct P1 { float k, s2, r; };
struct C1 { float A, bm, sQ; };

__device__ __forceinline__ P1 sp1(float lk, float ls) {
    P1 o;
    o.k = softplus_f(lk) + 1e-6f;
    float s = softplus_f(ls) + 1e-6f;
    o.s2 = s * s;
    o.r = o.s2 / fmaxf(2.f * o.k, 1e-12f);
    return o;
}

__device__ __forceinline__ P4 load_params4(const f4* __restrict__ mu4,
                                           const f4* __restrict__ lk4,
                                           const f4* __restrict__ ls4,
                                           int lane) {
    f4 lk = lk4[lane], ls = ls4[lane], mu = mu4[lane];
    P4 p;
    P1 a;
    a = sp1(lk.x, ls.x); p.k.x = a.k; p.s2.x = a.s2; p.r.x = a.r;
    a = sp1(lk.y, ls.y); p.k.y = a.k; p.s2.y = a.s2; p.r.y = a.r;
    a = sp1(lk.z, ls.z); p.k.z = a.k; p.s2.z = a.s2; p.r.z = a.r;
    a = sp1(lk.w, ls.w); p.k.w = a.k; p.s2.w = a.s2; p.r.w = a.r;
    p.mu = mu;
    return p;
}

// Exact OU transition coefficients (A = exp(-k dt); Q exact w/ Taylor fallback).
__device__ __forceinline__ C1 ou_coeff(float dt, float kappa, float s2, float r,
                                       float mu) {
    C1 o;
    float e = kappa * dt;
    o.A = __expf(-e);
    float two = 2.f * e;
    float Qe = r * (1.f - o.A * o.A);
    float Qt = s2 * dt * fmaf(two * two, (1.f / 6.f), 1.f - e);
    float Q = (two < 1e-6f) ? Qt : Qe;
    o.sQ = sqrtf(Q);
    o.bm = mu * (1.f - o.A);
    return o;
}

__device__ __forceinline__ C4 coeff4(float dt, const P4& p) {
    C4 c;
    C1 o;
    o = ou_coeff(dt, p.k.x, p.s2.x, p.r.x, p.mu.x); c.A.x = o.A; c.bm.x = o.bm; c.sQ.x = o.sQ;
    o = ou_coeff(dt, p.k.y, p.s2.y, p.r.y, p.mu.y); c.A.y = o.A; c.bm.y = o.bm; c.sQ.y = o.sQ;
    o = ou_coeff(dt, p.k.z, p.s2.z, p.r.z, p.mu.z); c.A.z = o.A; c.bm.z = o.bm; c.sQ.z = o.sQ;
    o = ou_coeff(dt, p.k.w, p.s2.w, p.r.w, p.mu.w); c.A.w = o.A; c.bm.w = o.bm; c.sQ.w = o.sQ;
    return c;
}

__device__ __forceinline__ f4 sqrt4(const f4 v) {
    f4 r;
    r.x = sqrtf(v.x); r.y = sqrtf(v.y); r.z = sqrtf(v.z); r.w = sqrtf(v.w);
    return r;
}

// -------------------- pass 1: local trajectories + partials --------------------
// Block (s, bg), wave w owns chain b. Reads noise ONCE (nontemporal: stream
// through, don't pollute L3), computes the segment-LOCAL trajectory
// yhat (started from 0; s=0 folds the true initial condition -> exact),
// writes yhat to out (regular stores: allocate in L3 for pass 3's RMW),
// and writes tiny partials: P = prod(A), U = yhat_end.
__global__ __launch_bounds__(256) void ou_local(
    const float* __restrict__ ts, const f4* __restrict__ noise4,
    const f4* __restrict__ mu4, const f4* __restrict__ lk4,
    const f4* __restrict__ ls4,
    f4* __restrict__ Pw, f4* __restrict__ Uw, f4* __restrict__ out4) {
    __shared__ float dts[LL];
    const int lane = threadIdx.x & 63;
    const int w = threadIdx.x >> 6;
    const int s = blockIdx.x / BPG;
    const int bg = blockIdx.x % BPG;
    const int b = bg * WPB + w;
    const int t0 = s * LL;

    if (threadIdx.x < LL) {
        int k = t0 + threadIdx.x;
        float dt = 1e-6f;
        if (k >= 1) dt = fmaxf(ts[k] - ts[k - 1], 1e-6f);
        dts[threadIdx.x] = dt;
    }
    __syncthreads();

    P4 p = load_params4(mu4, lk4, ls4, lane);
    const f4* np = noise4 + (size_t)b * TT * D4 + lane;
    f4* op = out4 + (size_t)b * TT * D4 + lane;

    f4 y = {0.f, 0.f, 0.f, 0.f};      // local trajectory, start 0
    f4 P = {1.f, 1.f, 1.f, 1.f};
    int kstart = t0;
    if (s == 0) {
        f4 n0 = __builtin_nontemporal_load(np);
        y = n0 * sqrt4(p.r) + p.mu;   // true initial condition
        P = (f4){0.f, 0.f, 0.f, 0.f}; // absorbing
        op[0] = y;
        kstart = 1;
    }

    float dtprev = -1.f;
    C4 cc;
#pragma unroll 4
    for (int k = kstart; k < t0 + LL; ++k) {
        float dt = dts[k - t0];
        f4 n = __builtin_nontemporal_load(np + (size_t)k * D4);
        if (dt != dtprev) { cc = coeff4(dt, p); dtprev = dt; } // wave-uniform
        f4 cv = cc.sQ * n + cc.bm;
        y = cc.A * y + cv;
        P *= cc.A;
        op[(size_t)k * D4] = y;       // regular store -> L3-resident for pass 3
    }

    size_t idx = ((size_t)s * BB + b) * D4 + lane;
    Pw[idx] = P;
    Uw[idx] = y;                      // U == yhat at segment end
}

// -------------------- pass 2: boundary scan over segments --------------------
// Ys[s,b] = true state at the START of segment s (= y_{s*LL-1}).
__global__ __launch_bounds__(64) void ou_bound(
    const f4* __restrict__ Pw, const f4* __restrict__ Uw,
    f4* __restrict__ Ys) {
    const int lane = threadIdx.x;
    const int b = blockIdx.x;
    const size_t stride = (size_t)BB * D4;
    const size_t i0 = (size_t)b * D4 + lane;

    f4 inc = Uw[i0]; // true y at end of segment 0 (P_0 = 0 absorbs)
#pragma unroll 8
    for (int s = 1; s < SS; ++s) {
        size_t idx = i0 + (size_t)s * stride;
        f4 Pv = Pw[idx];
        f4 Uv = Uw[idx];
        Ys[idx] = inc;
        inc = Pv * inc + Uv;
    }
}

// -------------------- pass 3: linear correction (no noise read!) -----------
// y[t] = yhat[t] + prefix(t) * ystart, prefix = running prod of per-step A
// (register-only). Reads yhat from L3 (just written), NT-stores the final.
// Reversed-s: read the hottest (most recently written) segments first.
// Segment 0 needs no correction and is excluded from the grid.
__global__ __launch_bounds__(256) void ou_correct(
    const float* __restrict__ ts, const f4* __restrict__ lk4,
    const f4* __restrict__ Ys, f4* __restrict__ out4) {
    __shared__ float dts[LL];
    const int lane = threadIdx.x & 63;
    const int w = threadIdx.x >> 6;
    const int s = (SS - 1) - (blockIdx.x / BPG);   // s in 63..1
    const int bg = blockIdx.x % BPG;
    const int b = bg * WPB + w;
    const int t0 = s * LL;

    if (threadIdx.x < LL) {
        int k = t0 + threadIdx.x;
        dts[threadIdx.x] = fmaxf(ts[k] - ts[k - 1], 1e-6f); // k >= 1 always (s>=1)
    }
    __syncthreads();

    // only kappa needed here
    f4 lk = lk4[lane];
    f4 kap;
    kap.x = softplus_f(lk.x) + 1e-6f;
    kap.y = softplus_f(lk.y) + 1e-6f;
    kap.z = softplus_f(lk.z) + 1e-6f;
    kap.w = softplus_f(lk.w) + 1e-6f;

    const f4 ystart = Ys[((size_t)s * BB + b) * D4 + lane];
    f4* op = out4 + (size_t)b * TT * D4 + lane;

    f4 prefix = {1.f, 1.f, 1.f, 1.f};
    float dtprev = -1.f;
    f4 A;
#pragma unroll 4
    for (int i = 0; i < LL; ++i) {
        float dt = dts[i];
        if (dt != dtprev) {
            A.x = __expf(-kap.x * dt);
            A.y = __expf(-kap.y * dt);
            A.z = __expf(-kap.z * dt);
            A.w = __expf(-kap.w * dt);
            dtprev = dt;
        }
        prefix *= A;
        f4 yh = op[(size_t)(t0 + i) * D4];   // L3 hit (freshly written)
        f4 y = prefix * ystart + yh;
        __builtin_nontemporal_store(y, op + (size_t)(t0 + i) * D4);
    }
}

// -------------------- last-resort fallback: plain per-chain scan ------------
__global__ __launch_bounds__(128) void ou_fallback(
    const float* __restrict__ ts, const float2* __restrict__ noise2,
    const float2* __restrict__ mu2, const float2* __restrict__ lk2,
    const float2* __restrict__ ls2, float2* __restrict__ out2) {
    __shared__ float dts[TT];
    const int tid = threadIdx.x;
    const int b = blockIdx.x;
    for (int i = tid; i < TT; i += 128) {
        float dt = 1e-6f;
        if (i >= 1) dt = fmaxf(ts[i] - ts[i - 1], 1e-6f);
        dts[i] = dt;
    }
    __syncthreads();

    float2 lk = lk2[tid], ls = ls2[tid], mu = mu2[tid];
    P1 px = sp1(lk.x, ls.x);
    P1 py = sp1(lk.y, ls.y);

    const float2* np = noise2 + (size_t)b * TT * 128 + tid;
    float2* op = out2 + (size_t)b * TT * 128 + tid;

    float2 n0 = np[0];
    float2 y;
    y.x = fmaf(n0.x, sqrtf(px.r), mu.x);
    y.y = fmaf(n0.y, sqrtf(py.r), mu.y);
    op[0] = y;

#pragma unroll 4
    for (int k = 1; k < TT; ++k) {
        float dt = dts[k];
        float2 n = np[(size_t)k * 128];
        C1 cx = ou_coeff(dt, px.k, px.s2, px.r, mu.x);
        C1 cy = ou_coeff(dt, py.k, py.s2, py.r, mu.y);
        y.x = fmaf(cx.A, y.x, fmaf(cx.sQ, n.x, cx.bm));
        y.y = fmaf(cy.A, y.y, fmaf(cy.sQ, n.y, cy.bm));
        op[(size_t)k * 128] = y;
    }
}

// -------------------- launch --------------------
extern "C" void kernel_launch(void* const* d_in, const int* in_sizes, int n_in,
                              void* d_out, int out_size, void* d_ws, size_t ws_size,
                              hipStream_t stream) {
    const float* ts = (const float*)d_in[0];
    const f4* noise4 = (const f4*)d_in[1];
    const f4* mu4 = (const f4*)d_in[2];
    const f4* lk4 = (const f4*)d_in[3];
    const f4* ls4 = (const f4*)d_in[4];
    f4* out4 = (f4*)d_out;

    const size_t seg = (size_t)SS * BB * D4; // f4 elements per ws buffer
    if (ws_size >= 3 * seg * sizeof(f4)) {
        f4* Pw = (f4*)d_ws;
        f4* Uw = Pw + seg;
        f4* Ys = Uw + seg;
        ou_local<<<SS * BPG, 256, 0, stream>>>(ts, noise4, mu4, lk4, ls4,
                                               Pw, Uw, out4);
        ou_bound<<<BB, 64, 0, stream>>>(Pw, Uw, Ys);
        ou_correct<<<(SS - 1) * BPG, 256, 0, stream>>>(ts, lk4, Ys, out4);
    } else {
        ou_fallback<<<BB, 128, 0, stream>>>(ts, (const float2*)d_in[1],
                                            (const float2*)d_in[2],
                                            (const float2*)d_in[3],
                                            (const float2*)d_in[4],
                                            (float2*)d_out);
    }
}